// Round 11
// baseline (368.662 us; speedup 1.0000x reference)
//
#include <hip/hip_runtime.h>

#if __has_builtin(__builtin_amdgcn_exp2f)
#define EXP2F(x) __builtin_amdgcn_exp2f(x)
#else
#define EXP2F(x) exp2f(x)
#endif
#if __has_builtin(__builtin_amdgcn_rcpf)
#define RCPF(x) __builtin_amdgcn_rcpf(x)
#else
#define RCPF(x) (1.0f / (x))
#endif

namespace {

constexpr int B_ = 2048, T_ = 512, D_ = 8, H_ = 20, L_ = 10;
constexpr int NG    = 16;        // batch group per block (MFMA N)
constexpr int PADK  = 40;        // bf16 elems per [batch] row (80 B)
constexpr int NW    = 11;        // 10 layer waves + 1 head wave
constexpr int NTHR  = NW * 64;   // 704
constexpr int DEPTH = 8;         // h ring depth (cached-poll slack)
constexpr int SLOT_STRIDE  = L_ * NG * PADK;  // 6400 shorts
constexpr int LAYER_STRIDE = NG * PADK;       // 640 shorts

typedef float f32x4 __attribute__((ext_vector_type(4)));
typedef short s16x8 __attribute__((ext_vector_type(8)));
typedef unsigned u32x4 __attribute__((ext_vector_type(4)));

#define LD4(p) (*reinterpret_cast<const f32x4*>(p))

__device__ __forceinline__ unsigned short f2bf(float f) {
    unsigned u = __builtin_bit_cast(unsigned, f);
    return (unsigned short)((u + 0x7FFFu + ((u >> 16) & 1u)) >> 16);
}
__device__ __forceinline__ float bf2f(unsigned short b) {
    return __builtin_bit_cast(float, (unsigned)b << 16);
}
__device__ __forceinline__ unsigned cvt_pk_bf16(float s0, float s1) {
    unsigned r;
    asm("v_cvt_pk_bf16_f32 %0, %1, %2" : "=v"(r) : "v"(s0), "v"(s1));
    return r;
}
__device__ __forceinline__ f32x4 mfma_bf16(s16x8 a, s16x8 b, f32x4 c) {
    return __builtin_amdgcn_mfma_f32_16x16x32_bf16(a, b, c, 0, 0, 0);
}
__device__ __forceinline__ float tanh_fast(float x) {
    float e = EXP2F(x * 2.8853900817779268f);
    return fmaf(-2.0f, RCPF(1.0f + e), 1.0f);
}

// acquire-poll, returns the freshest value (enables register caching)
__device__ __forceinline__ int wait_ge_ret(int* p, int v) {
    int cur = __hip_atomic_load(p, __ATOMIC_ACQUIRE, __HIP_MEMORY_SCOPE_WORKGROUP);
    while (cur < v)
        cur = __hip_atomic_load(p, __ATOMIC_ACQUIRE, __HIP_MEMORY_SCOPE_WORKGROUP);
    __builtin_amdgcn_sched_barrier(0);
    return cur;
}
// LDS-only release: lgkmcnt(0) orders h-stores before the flag (R10 lesson:
// vmcnt drain was NOT the wall, but keep it out anyway)
__device__ __forceinline__ void publish(int* p, int v) {
    asm volatile("s_waitcnt lgkmcnt(0)" ::: "memory");
    __hip_atomic_store(p, v, __ATOMIC_RELAXED, __HIP_MEMORY_SCOPE_WORKGROUP);
}

// pack 8 f32 -> per-lane bf16 frag variant (hi for g==0, lo for g==1)
__device__ __forceinline__ s16x8 pack_x(f32x4 a, f32x4 b, bool lo) {
    s16x8 r;
    #pragma unroll
    for (int e = 0; e < 8; ++e) {
        float f = (e < 4) ? a[e] : b[e - 4];
        unsigned short hb = f2bf(f);
        r[e] = (short)(lo ? f2bf(f - bf2f(hb)) : hb);
    }
    return r;
}

// R11: LDS-latency-chain fix. R8/R9/R10 all ~360-430us because each step
// serialized ~7 LDS round-trips on the h[t]->h[t+1] recurrence. Now:
// (1) own-h B1 never touches LDS: h kept packed in regs (pw,qw), D->B
//     fragment transpose done in-wave via 6 ds_bpermute (__shfl);
// (2) loop rotated: store h[t-1]+publish at top of iter t (overlaps MFMA);
// (3) prog polls cached in registers, DEPTH=8 ring -> ~1 poll per many steps.
__global__ __launch_bounds__(NTHR) void rnn_async(
    const float* __restrict__ x,      // [B,T,8]
    const float* __restrict__ w_ih0,  // [20,8]
    const float* __restrict__ w_ih,   // [9,20,20]
    const float* __restrict__ w_hh,   // [10,20,20]
    const float* __restrict__ b_ih,   // [10,20]
    const float* __restrict__ b_hh,   // [10,20]
    const float* __restrict__ fc_w,   // [20,20]
    const float* __restrict__ fc_b,   // [20]
    const float* __restrict__ l2_w,   // [1,20]
    const float* __restrict__ l2_b,   // [1]
    float* __restrict__ out)          // [B,T] flat
{
    __shared__ __align__(16) unsigned short h_lds[DEPTH][L_][NG][PADK]; // 102.4KB
    __shared__ int prog[16];

    const int tid = threadIdx.x;
    const int w   = tid >> 6;       // 0..9 layer wave, 10 head wave
    const int l   = tid & 63;
    const int col = l & 15;
    const int g   = l >> 4;
    const int bg  = blockIdx.x * NG;

    // zero ring (only the k>=20 pad matters after warmup) + prog
    {
        uint4* p4 = reinterpret_cast<uint4*>(&h_lds[0][0][0][0]);
        const int n4 = DEPTH * L_ * NG * PADK / 8;
        for (int i = tid; i < n4; i += NTHR) p4[i] = make_uint4(0, 0, 0, 0);
        if (tid < 16) prog[tid] = 0;
    }

    // ---- A fragments (hi/lo split), biases, head constants (as R8-R10) ----
    s16x8 a0_hi = {0,0,0,0,0,0,0,0}, a0_lo = a0_hi, a1_hi = a0_hi, a1_lo = a0_hi;
    s16x8 h0_hi = a0_hi, h0_lo = a0_hi, h1_hi = a0_hi, h1_lo = a0_hi;
    f32x4 bias0 = {0.f, 0.f, 0.f, 0.f}, bias1 = bias0;
    f32x4 l2v0 = bias0, l2v1 = bias0;
    float l2bv = 0.f;
    const bool mt1ok = col < (H_ - 16);

    if (w < L_) {
        const int layer = w;
        #pragma unroll
        for (int e = 0; e < 8; ++e) {
            const int k = g * 8 + e;
            float wv0 = 0.f, wv1 = 0.f;
            if (layer == 0) {
                if (k < 16) {
                    wv0 = w_ih0[col * D_ + (k & 7)];
                    if (mt1ok) wv1 = w_ih0[(16 + col) * D_ + (k & 7)];
                }
            } else if (k < H_) {
                wv0 = w_ih[((layer - 1) * H_ + col) * H_ + k];
                if (mt1ok) wv1 = w_ih[((layer - 1) * H_ + 16 + col) * H_ + k];
            }
            unsigned short b0 = f2bf(wv0), b1 = f2bf(wv1);
            a0_hi[e] = (short)b0; a0_lo[e] = (short)f2bf(wv0 - bf2f(b0));
            a1_hi[e] = (short)b1; a1_lo[e] = (short)f2bf(wv1 - bf2f(b1));
            float uv0 = 0.f, uv1 = 0.f;
            if (k < H_) {
                uv0 = w_hh[(layer * H_ + col) * H_ + k];
                if (mt1ok) uv1 = w_hh[(layer * H_ + 16 + col) * H_ + k];
            }
            unsigned short c0 = f2bf(uv0), c1 = f2bf(uv1);
            h0_hi[e] = (short)c0; h0_lo[e] = (short)f2bf(uv0 - bf2f(c0));
            h1_hi[e] = (short)c1; h1_lo[e] = (short)f2bf(uv1 - bf2f(c1));
        }
        #pragma unroll
        for (int r = 0; r < 4; ++r) {
            const int row = g * 4 + r;
            bias0[r] = b_ih[layer * H_ + row] + b_hh[layer * H_ + row];
            bias1[r] = (g == 0) ? (b_ih[layer * H_ + 16 + r] +
                                   b_hh[layer * H_ + 16 + r]) : 0.f;
        }
    } else {
        #pragma unroll
        for (int e = 0; e < 8; ++e) {
            const int k = g * 8 + e;
            float f0 = 0.f, f1 = 0.f;
            if (k < H_) {
                f0 = fc_w[col * H_ + k];
                if (mt1ok) f1 = fc_w[(16 + col) * H_ + k];
            }
            unsigned short b0 = f2bf(f0), b1 = f2bf(f1);
            a0_hi[e] = (short)b0; a0_lo[e] = (short)f2bf(f0 - bf2f(b0));
            a1_hi[e] = (short)b1; a1_lo[e] = (short)f2bf(f1 - bf2f(b1));
        }
        #pragma unroll
        for (int r = 0; r < 4; ++r) {
            bias0[r] = fc_b[g * 4 + r];
            bias1[r] = (g == 0) ? fc_b[16 + r] : 0.f;
            l2v0[r]  = l2_w[g * 4 + r];
            l2v1[r]  = (g == 0) ? l2_w[16 + r] : 0.f;
        }
        l2bv = l2_b[0];
    }

    // D->B transpose shfl source lanes (fixed per lane)
    const int i0 = (g == 1) ? col + 32 : col;
    const int i1 = (g == 0) ? col + 16 : ((g == 1) ? col + 48 : col);

    // wave-0 x prefetch, 2 deep, packed at load (4 VGPR/slot)
    s16x8 xf_cur = {0,0,0,0,0,0,0,0}, xf_nxt = xf_cur;
    if (w == 0 && g < 2) {
        const float* xp = x + (size_t)(bg + col) * T_ * D_;
        xf_cur = pack_x(LD4(xp), LD4(xp + 4), g == 1);
        xf_nxt = pack_x(LD4(xp + D_), LD4(xp + D_ + 4), g == 1);
    }

    __syncthreads();  // init + frags visible; ONLY barrier

    unsigned short* const hb = &h_lds[0][0][0][0];
    const f32x4 z4 = {0.f, 0.f, 0.f, 0.f};

    if (w < L_) {
        const int rdB0 = (w ? (w - 1) * LAYER_STRIDE : 0) + col * PADK + g * 8;
        const int wr0  = w * LAYER_STRIDE + col * PADK + g * 4;
        const int wr1  = w * LAYER_STRIDE + col * PADK + 16;
        uint2 pw = make_uint2(0u, 0u), qw = pw;   // h[t-1] packed (t=0: zeros)
        int p_up = 0, p_dn = 0;
        for (int t = 0; t < T_; ++t) {
            // ---- B1 = own h[t-1], in-wave D->B transpose (no LDS mem) ----
            unsigned s0 = __shfl(pw.x, i0), s1 = __shfl(pw.y, i0);
            unsigned s2 = __shfl(pw.x, i1), s3 = __shfl(pw.y, i1);
            unsigned u0 = __shfl(qw.x, col), u1 = __shfl(qw.y, col);
            u32x4 bw;
            bw[0] = (g < 2) ? s0 : ((g == 2) ? u0 : 0u);
            bw[1] = (g < 2) ? s1 : ((g == 2) ? u1 : 0u);
            bw[2] = (g < 2) ? s2 : 0u;
            bw[3] = (g < 2) ? s3 : 0u;
            s16x8 B1 = __builtin_bit_cast(s16x8, bw);
            // ---- store h[t-1] for downstream + publish (off critical path) ----
            if (t > 0) {
                const int sp = ((t - 1) & (DEPTH - 1)) * SLOT_STRIDE;
                if (t - 1 >= DEPTH && p_dn < t - DEPTH)
                    p_dn = wait_ge_ret(&prog[w + 1], t - DEPTH);
                *reinterpret_cast<uint2*>(hb + sp + wr0) = pw;
                if (g == 0) *reinterpret_cast<uint2*>(hb + sp + wr1) = qw;
                if (l == 0) publish(&prog[w], t);
            }
            // ---- B0 = input from below (LDS) or packed x ----
            s16x8 B0;
            if (w == 0) {
                B0 = xf_cur;
                xf_cur = xf_nxt;
                if (g < 2 && t + 2 < T_) {
                    const float* xp = x + ((size_t)(bg + col) * T_ + t + 2) * D_;
                    xf_nxt = pack_x(LD4(xp), LD4(xp + 4), g == 1);
                }
            } else {
                if (p_up < t + 1) p_up = wait_ge_ret(&prog[w - 1], t + 1);
                B0 = *reinterpret_cast<const s16x8*>(
                    hb + (t & (DEPTH - 1)) * SLOT_STRIDE + rdB0);
            }
            // ---- MFMA (two parallel 2-deep hi/lo chains) ----
            f32x4 A  = mfma_bf16(h0_hi, B1, bias0);
            f32x4 Ab = mfma_bf16(h0_lo, B1, z4);
            f32x4 C  = mfma_bf16(h1_hi, B1, bias1);
            f32x4 Cb = mfma_bf16(h1_lo, B1, z4);
            A  = mfma_bf16(a0_hi, B0, A);
            Ab = mfma_bf16(a0_lo, B0, Ab);
            C  = mfma_bf16(a1_hi, B0, C);
            Cb = mfma_bf16(a1_lo, B0, Cb);
            f32x4 acc0 = A + Ab, acc1 = C + Cb;
            pw.x = cvt_pk_bf16(tanh_fast(acc0[0]), tanh_fast(acc0[1]));
            pw.y = cvt_pk_bf16(tanh_fast(acc0[2]), tanh_fast(acc0[3]));
            qw.x = cvt_pk_bf16(tanh_fast(acc1[0]), tanh_fast(acc1[1]));
            qw.y = cvt_pk_bf16(tanh_fast(acc1[2]), tanh_fast(acc1[3]));
        }
        // tail: store h[T-1], publish T
        {
            const int sp = ((T_ - 1) & (DEPTH - 1)) * SLOT_STRIDE;
            if (p_dn < T_ - DEPTH) wait_ge_ret(&prog[w + 1], T_ - DEPTH);
            *reinterpret_cast<uint2*>(hb + sp + wr0) = pw;
            if (g == 0) *reinterpret_cast<uint2*>(hb + sp + wr1) = qw;
            if (l == 0) publish(&prog[w], T_);
        }
    } else {
        // head wave: y[t] from h[9][t]
        const int rdH = (L_ - 1) * LAYER_STRIDE + col * PADK + g * 8;
        int p_up = 0;
        for (int t = 0; t < T_; ++t) {
            if (p_up < t + 1) p_up = wait_ge_ret(&prog[L_ - 1], t + 1);
            s16x8 Bh = *reinterpret_cast<const s16x8*>(
                hb + (t & (DEPTH - 1)) * SLOT_STRIDE + rdH);
            f32x4 z0  = mfma_bf16(a0_hi, Bh, bias0);
            f32x4 z0b = mfma_bf16(a0_lo, Bh, z4);
            f32x4 z1  = mfma_bf16(a1_hi, Bh, bias1);
            f32x4 z1b = mfma_bf16(a1_lo, Bh, z4);
            z0 += z0b; z1 += z1b;
            float part = 0.f;
            #pragma unroll
            for (int r = 0; r < 4; ++r) {
                part = fmaf(l2v0[r], fmaxf(z0[r], 0.f), part);
                part = fmaf(l2v1[r], fmaxf(z1[r], 0.f), part);
            }
            part += __shfl_xor(part, 16);
            part += __shfl_xor(part, 32);
            if (l < NG) out[(size_t)(bg + l) * T_ + t] = part + l2bv;
            if (l == 0) publish(&prog[L_], t + 1);  // "Bh[t] read done"
        }
    }
}

}  // namespace

extern "C" void kernel_launch(void* const* d_in, const int* in_sizes, int n_in,
                              void* d_out, int out_size, void* d_ws, size_t ws_size,
                              hipStream_t stream) {
    const float* x     = (const float*)d_in[0];
    const float* w_ih0 = (const float*)d_in[1];
    const float* w_ih  = (const float*)d_in[2];
    const float* w_hh  = (const float*)d_in[3];
    const float* b_ih  = (const float*)d_in[4];
    const float* b_hh  = (const float*)d_in[5];
    const float* fc_w  = (const float*)d_in[6];
    const float* fc_b  = (const float*)d_in[7];
    const float* l2_w  = (const float*)d_in[8];
    const float* l2_b  = (const float*)d_in[9];
    float* out = (float*)d_out;

    const int grid = B_ / NG;  // 128
    hipLaunchKernelGGL(rnn_async, dim3(grid), dim3(NTHR), 0, stream,
                       x, w_ih0, w_ih, w_hh, b_ih, b_hh, fc_w, fc_b,
                       l2_w, l2_b, out);
}